// Round 10
// baseline (87.492 us; speedup 1.0000x reference)
//
#include <hip/hip_runtime.h>

#define NB   8192
#define NT   2048
#define OBS  30
#define LCH  64               // chunk length == wave size
#define CCH  32               // chunks per row
#define RPB  4                // rows per block
#define NTHR 128              // = RPB*CCH chunks; 2 waves
#define CSTR 68               // chunk stride (17 float4, odd -> <=2-way banks)

// One recurrence step on a 32-slot register ring, 6 accumulator chains.
// Invariant: before step t, state s_t[i] lives at r[(t+i)&31], i=0..29.
// j == t mod 32 must be a compile-time constant (callers fully unroll).
__device__ __forceinline__ float step6(float (&r)[32], const float (&wx)[OBS],
                                       int j, float uwf) {
  float a0 = fmaf(wx[0], r[(j + 0) & 31], uwf);
  float a1 = wx[1] * r[(j + 1) & 31];
  float a2 = wx[2] * r[(j + 2) & 31];
  float a3 = wx[3] * r[(j + 3) & 31];
  float a4 = wx[4] * r[(j + 4) & 31];
  float a5 = wx[5] * r[(j + 5) & 31];
  #pragma unroll
  for (int i = 6; i < OBS; i += 6) {
    a0 = fmaf(wx[i],     r[(j + i)     & 31], a0);
    a1 = fmaf(wx[i + 1], r[(j + i + 1) & 31], a1);
    a2 = fmaf(wx[i + 2], r[(j + i + 2) & 31], a2);
    a3 = fmaf(wx[i + 3], r[(j + i + 3) & 31], a3);
    a4 = fmaf(wx[i + 4], r[(j + i + 4) & 31], a4);
    a5 = fmaf(wx[i + 5], r[(j + i + 5) & 31], a5);
  }
  float out = ((a0 + a1) + (a2 + a3)) + (a4 + a5);
  r[(j + 30) & 31] = out;
  return out;
}

// wave-uniform broadcast of lane `lane`'s value (VALU pipe, SGPR result)
__device__ __forceinline__ float rl(float v, int lane) {
  return __uint_as_float(__builtin_amdgcn_readlane(__float_as_uint(v), lane));
}

// Fully fused. Block: 128 threads (2 waves) own 4 rows.
// Phase 2: lane <-> chunk (128 chunks). Phase 3: wave <-> row (2 rows/wave),
// lane k <-> output t=k of each chunk; state broadcast via v_readlane.
__global__ void __launch_bounds__(NTHR, 2)
k_fused(const float* __restrict__ u, const float* __restrict__ x0,
        const float* __restrict__ Wx, const float* __restrict__ Wf,
        float* __restrict__ out) {
  __shared__ float tile[RPB * CCH * CSTR];   // 34.8 KB; C overlaid early
  const int tid  = threadIdx.x;
  const int wv   = tid >> 6;
  const int k    = tid & 63;
  const int row0 = blockIdx.x * RPB;

  float wx[OBS];
  #pragma unroll
  for (int i = 0; i < OBS; ++i) wx[i] = Wx[i];
  const float wf = Wf[0];

  // ---- issue all u loads early (land while C is computed)
  float4 stg[16];
  const float* ub = u + (size_t)row0 * NT;
  #pragma unroll
  for (int i = 0; i < 16; ++i) {
    int v = i * NTHR + tid, rr = v >> 9, p = v & 511;
    stg[i] = *(const float4*)(ub + (size_t)rr * NT + 4 * p);
  }

  // ---- C[t][i] (t<64, i<30): homogeneous out at step t from unit state e_i.
  // Lane i runs column i; overlaid on tile (stride 33), consumed before stage.
  if (tid < 32) {
    float r[32];
    #pragma unroll
    for (int i = 0; i < 32; ++i) r[i] = (tid < OBS && i == tid) ? 1.f : 0.f;
    #pragma unroll
    for (int q = 0; q < 16; ++q)
      #pragma unroll
      for (int e = 0; e < 4; ++e) {
        float o = step6(r, wx, (4 * q + e) & 31, 0.f);
        if (tid < OBS) tile[(4 * q + e) * 33 + tid] = o;
      }
  }
  __syncthreads();
  float c0[OBS];                       // my output row t=k: C[k][0..29]
  #pragma unroll
  for (int i = 0; i < OBS; ++i) c0[i] = tile[k * 33 + i];  // (k+i)%32: 2-way
  __syncthreads();                     // C consumed; tile reusable

  // ---- stage u chunk-major: tile[(row*CCH+chunk)*CSTR + t]
  #pragma unroll
  for (int i = 0; i < 16; ++i) {
    int v = i * NTHR + tid, rr = v >> 9, p = v & 511;
    int c = p >> 4, q = p & 15;
    *(float4*)(&tile[(rr * CCH + c) * CSTR + 4 * q]) = stg[i];
  }
  __syncthreads();

  // ---- phase 2: zero-init particular recurrence; lane == chunk tid
  {
    float r[32];
    #pragma unroll
    for (int i = 0; i < 32; ++i) r[i] = 0.f;
    float* tc = &tile[tid * CSTR];     // (rr*CCH + c) == tid
    #pragma unroll
    for (int q = 0; q < 16; ++q) {
      float4 u4 = *(const float4*)(tc + 4 * q);
      float4 o4;
      o4.x = step6(r, wx, (4 * q + 0) & 31, wf * u4.x);
      o4.y = step6(r, wx, (4 * q + 1) & 31, wf * u4.y);
      o4.z = step6(r, wx, (4 * q + 2) & 31, wf * u4.z);
      o4.w = step6(r, wx, (4 * q + 3) & 31, wf * u4.w);
      *(float4*)(tc + 4 * q) = o4;
    }
  }
  __syncthreads();

  // ---- phase 3: serial chunk scan + correction; wave owns rows wv*2, wv*2+1
  #pragma unroll 1
  for (int rr2 = 0; rr2 < 2; ++rr2) {
    const int lr  = wv * 2 + rr2;
    const int row = row0 + lr;
    // chunk-start state for c=0 lives in lanes 34..63 (matches out[34..63])
    float vprev = (k >= 34) ? x0[(size_t)row * OBS + (k - 34)] : 0.f;
    const float* trow = &tile[lr * CCH * CSTR];
    float* orow = out + (size_t)row * NT;
    #pragma unroll 1
    for (int c = 0; c < CCH; ++c) {
      float sv[OBS];
      #pragma unroll
      for (int i = 0; i < OBS; ++i) sv[i] = rl(vprev, 34 + i);  // VALU, SGPRs
      float p = trow[c * CSTR + k];    // particular out; (4c+k)%32: 2-way
      float a0 = fmaf(c0[0], sv[0], p);
      float a1 = c0[1] * sv[1];
      float a2 = c0[2] * sv[2];
      float a3 = c0[3] * sv[3];
      float a4 = c0[4] * sv[4];
      float a5 = c0[5] * sv[5];
      #pragma unroll
      for (int i = 6; i < OBS; i += 6) {
        a0 = fmaf(c0[i],     sv[i],     a0);
        a1 = fmaf(c0[i + 1], sv[i + 1], a1);
        a2 = fmaf(c0[i + 2], sv[i + 2], a2);
        a3 = fmaf(c0[i + 3], sv[i + 3], a3);
        a4 = fmaf(c0[i + 4], sv[i + 4], a4);
        a5 = fmaf(c0[i + 5], sv[i + 5], a5);
      }
      float t0 = ((a0 + a1) + (a2 + a3)) + (a4 + a5);  // true out, t = c*64+k
      orow[c * 64 + k] = t0;           // 256B contiguous per wave: coalesced
      vprev = t0;                      // lanes 34..63 feed next chunk's state
    }
  }
}

extern "C" void kernel_launch(void* const* d_in, const int* in_sizes, int n_in,
                              void* d_out, int out_size, void* d_ws, size_t ws_size,
                              hipStream_t stream) {
  const float* u  = (const float*)d_in[0];
  const float* x0 = (const float*)d_in[1];
  const float* Wx = (const float*)d_in[2];
  const float* Wf = (const float*)d_in[3];
  float* out = (float*)d_out;

  hipLaunchKernelGGL(k_fused, dim3(NB / RPB), dim3(NTHR), 0, stream,
                     u, x0, Wx, Wf, out);
}

// Round 11
// 73.653 us; speedup vs baseline: 1.1879x; 1.1879x over previous
//
#include <hip/hip_runtime.h>

#define NB   8192
#define NT   2048
#define OBS  30
#define LCH  64               // chunk length (phase 2 & 3)
#define CCH  32               // chunks per row
#define RPB  4                // rows per block
#define NTHR 128              // = RPB*CCH chunks in phase 2; 2 waves
#define CSTR 68               // chunk stride in floats (17 float4)

// One recurrence step on a 32-slot register ring, 6 accumulator chains.
// Invariant: before step t, state s_t[i] lives at r[(t+i)&31], i=0..29.
// j == t mod 32 must be a compile-time constant (callers fully unroll).
__device__ __forceinline__ float step6(float (&r)[32], const float (&wx)[OBS],
                                       int j, float uwf) {
  float a0 = fmaf(wx[0], r[(j + 0) & 31], uwf);
  float a1 = wx[1] * r[(j + 1) & 31];
  float a2 = wx[2] * r[(j + 2) & 31];
  float a3 = wx[3] * r[(j + 3) & 31];
  float a4 = wx[4] * r[(j + 4) & 31];
  float a5 = wx[5] * r[(j + 5) & 31];
  #pragma unroll
  for (int i = 6; i < OBS; i += 6) {
    a0 = fmaf(wx[i],     r[(j + i)     & 31], a0);
    a1 = fmaf(wx[i + 1], r[(j + i + 1) & 31], a1);
    a2 = fmaf(wx[i + 2], r[(j + i + 2) & 31], a2);
    a3 = fmaf(wx[i + 3], r[(j + i + 3) & 31], a3);
    a4 = fmaf(wx[i + 4], r[(j + i + 4) & 31], a4);
    a5 = fmaf(wx[i + 5], r[(j + i + 5) & 31], a5);
  }
  float out = ((a0 + a1) + (a2 + a3)) + (a4 + a5);
  r[(j + 30) & 31] = out;
  return out;
}

// Fully fused. Block: 128 threads (2 waves) own 4 rows.
// Phase 2: thread <-> 64-long chunk (128 chunks). Phase 3: 32-lane group <->
// row; lane k owns outputs t=k and t=32+k of each chunk; state broadcast via
// 8 ds_read_b128 of the group's 128B slot, amortized over 64 outputs.
__global__ void __launch_bounds__(NTHR, 2)
k_fused(const float* __restrict__ u, const float* __restrict__ x0,
        const float* __restrict__ Wx, const float* __restrict__ Wf,
        float* __restrict__ out) {
  __shared__ float tile[RPB * CCH * CSTR];   // 34.8 KB: [row][chunk][68]
  __shared__ float sbuf[RPB * 32];           // per-group running state slot
  const int tid  = threadIdx.x;
  const int g    = tid >> 5, k = tid & 31;
  const int row0 = blockIdx.x * RPB;

  float wx[OBS];
  #pragma unroll
  for (int i = 0; i < OBS; ++i) wx[i] = Wx[i];
  const float wf = Wf[0];

  // ---- issue all u loads early (land while C is computed)
  float4 stg[16];
  const float* ub = u + (size_t)row0 * NT;
  #pragma unroll
  for (int i = 0; i < 16; ++i) {
    int v = i * NTHR + tid, rr = v >> 9, p = v & 511;
    stg[i] = *(const float4*)(ub + (size_t)rr * NT + 4 * p);
  }

  // ---- C[t][i] (t<64, i<30): homogeneous out at step t from unit state e_i.
  // Lane i runs column i; stored to tile (stride 33), consumed before staging.
  if (tid < 32) {
    float r[32];
    #pragma unroll
    for (int i = 0; i < 32; ++i) r[i] = (tid < OBS && i == tid) ? 1.f : 0.f;
    #pragma unroll
    for (int q = 0; q < 16; ++q)
      #pragma unroll
      for (int e = 0; e < 4; ++e) {
        float o = step6(r, wx, (4 * q + e) & 31, 0.f);
        if (tid < OBS) tile[(4 * q + e) * 33 + tid] = o;
      }
  }
  __syncthreads();
  float c0[OBS], c1[OBS];              // my two C rows: t=k and t=32+k
  #pragma unroll
  for (int i = 0; i < OBS; ++i) c0[i] = tile[k * 33 + i];
  #pragma unroll
  for (int i = 0; i < OBS; ++i) c1[i] = tile[(32 + k) * 33 + i];
  sbuf[g * 32 + k] = (k < OBS) ? x0[(size_t)(row0 + g) * OBS + k] : 0.f;
  __syncthreads();                     // C consumed; tile reusable

  // ---- stage u chunk-major: tile[(row*CCH+chunk)*CSTR + t]
  #pragma unroll
  for (int i = 0; i < 16; ++i) {
    int v = i * NTHR + tid, rr = v >> 9, p = v & 511;
    int c = p >> 4, q = p & 15;
    *(float4*)(&tile[(rr * CCH + c) * CSTR + 4 * q]) = stg[i];
  }
  __syncthreads();

  // ---- phase 2: zero-init particular recurrence; thread <-> chunk (64 steps)
  {
    float r[32];
    #pragma unroll
    for (int i = 0; i < 32; ++i) r[i] = 0.f;
    float* tc = &tile[tid * CSTR];
    #pragma unroll
    for (int q = 0; q < 16; ++q) {
      float4 u4 = *(const float4*)(tc + 4 * q);
      float4 o4;
      o4.x = step6(r, wx, (4 * q + 0) & 31, wf * u4.x);
      o4.y = step6(r, wx, (4 * q + 1) & 31, wf * u4.y);
      o4.z = step6(r, wx, (4 * q + 2) & 31, wf * u4.z);
      o4.w = step6(r, wx, (4 * q + 3) & 31, wf * u4.w);
      *(float4*)(tc + 4 * q) = o4;
    }
  }
  __syncthreads();

  // ---- phase 3: serial chunk scan + correction; group g owns row row0+g
  float* sl = &sbuf[g * 32];
  const float* trow = &tile[(g * CCH) * CSTR];
  float* orow = out + (size_t)(row0 + g) * NT;
  #pragma unroll 1
  for (int c = 0; c < CCH; ++c) {
    float sv[32];
    #pragma unroll
    for (int q = 0; q < 8; ++q) {      // broadcast b128: one 128B slot/group
      float4 v = *(const float4*)(sl + 4 * q);
      sv[4 * q] = v.x; sv[4 * q + 1] = v.y;
      sv[4 * q + 2] = v.z; sv[4 * q + 3] = v.w;
    }
    // serial-path output first: t = c*64 + 32 + k feeds the next state
    float p1 = trow[c * CSTR + 32 + k];
    float b0 = fmaf(c1[0], sv[0], p1);
    float b1 = c1[1] * sv[1];
    float b2 = c1[2] * sv[2];
    float b3 = c1[3] * sv[3];
    float b4 = c1[4] * sv[4];
    float b5 = c1[5] * sv[5];
    #pragma unroll
    for (int i = 6; i < OBS; i += 6) {
      b0 = fmaf(c1[i],     sv[i],     b0);
      b1 = fmaf(c1[i + 1], sv[i + 1], b1);
      b2 = fmaf(c1[i + 2], sv[i + 2], b2);
      b3 = fmaf(c1[i + 3], sv[i + 3], b3);
      b4 = fmaf(c1[i + 4], sv[i + 4], b4);
      b5 = fmaf(c1[i + 5], sv[i + 5], b5);
    }
    float t1 = ((b0 + b1) + (b2 + b3)) + (b4 + b5);
    if (k >= 2) sl[k - 2] = t1;        // s_next[i] = out[34+i] = t1 of lane 2+i
    // off-serial-path output: t = c*64 + k
    float p0 = trow[c * CSTR + k];
    float a0 = fmaf(c0[0], sv[0], p0);
    float a1 = c0[1] * sv[1];
    float a2 = c0[2] * sv[2];
    float a3 = c0[3] * sv[3];
    float a4 = c0[4] * sv[4];
    float a5 = c0[5] * sv[5];
    #pragma unroll
    for (int i = 6; i < OBS; i += 6) {
      a0 = fmaf(c0[i],     sv[i],     a0);
      a1 = fmaf(c0[i + 1], sv[i + 1], a1);
      a2 = fmaf(c0[i + 2], sv[i + 2], a2);
      a3 = fmaf(c0[i + 3], sv[i + 3], a3);
      a4 = fmaf(c0[i + 4], sv[i + 4], a4);
      a5 = fmaf(c0[i + 5], sv[i + 5], a5);
    }
    float t0 = ((a0 + a1) + (a2 + a3)) + (a4 + a5);
    orow[c * 64 + k]      = t0;        // 256B per wave instr: coalesced
    orow[c * 64 + 32 + k] = t1;
    __builtin_amdgcn_wave_barrier();   // fence slot write vs next iter's reads
  }
}

extern "C" void kernel_launch(void* const* d_in, const int* in_sizes, int n_in,
                              void* d_out, int out_size, void* d_ws, size_t ws_size,
                              hipStream_t stream) {
  const float* u  = (const float*)d_in[0];
  const float* x0 = (const float*)d_in[1];
  const float* Wx = (const float*)d_in[2];
  const float* Wf = (const float*)d_in[3];
  float* out = (float*)d_out;

  hipLaunchKernelGGL(k_fused, dim3(NB / RPB), dim3(NTHR), 0, stream,
                     u, x0, Wx, Wf, out);
}

// Round 12
// 51.636 us; speedup vs baseline: 1.6944x; 1.4264x over previous
//
#include <hip/hip_runtime.h>

#define NB   8192
#define NT   2048
#define OBS  30
#define CCH  32               // 64-long chunks per row
#define RPB  8                // rows per block
#define NTHR 256              // 4 waves == RPB*CCH chunks for phase 2
#define CSTR 68               // chunk stride (17 float4)

// One recurrence step on a 32-slot register ring, 6 accumulator chains.
// Invariant: before step t, state s_t[i] lives at r[(t+i)&31], i=0..29.
// j == t mod 32 must be a compile-time constant (callers fully unroll).
__device__ __forceinline__ float step6(float (&r)[32], const float (&wx)[OBS],
                                       int j, float uwf) {
  float a0 = fmaf(wx[0], r[(j + 0) & 31], uwf);
  float a1 = wx[1] * r[(j + 1) & 31];
  float a2 = wx[2] * r[(j + 2) & 31];
  float a3 = wx[3] * r[(j + 3) & 31];
  float a4 = wx[4] * r[(j + 4) & 31];
  float a5 = wx[5] * r[(j + 5) & 31];
  #pragma unroll
  for (int i = 6; i < OBS; i += 6) {
    a0 = fmaf(wx[i],     r[(j + i)     & 31], a0);
    a1 = fmaf(wx[i + 1], r[(j + i + 1) & 31], a1);
    a2 = fmaf(wx[i + 2], r[(j + i + 2) & 31], a2);
    a3 = fmaf(wx[i + 3], r[(j + i + 3) & 31], a3);
    a4 = fmaf(wx[i + 4], r[(j + i + 4) & 31], a4);
    a5 = fmaf(wx[i + 5], r[(j + i + 5) & 31], a5);
  }
  float out = ((a0 + a1) + (a2 + a3)) + (a4 + a5);
  r[(j + 30) & 31] = out;
  return out;
}

// Fully fused. Block: 256 threads (4 waves) own 8 rows.
// Phase 2: thread <-> 64-long chunk (256 chunks). Phase 3: wave <-> 2 rows
// (32-lane groups share every DS wave-instruction); lane k owns outputs
// t=2k, 2k+1 of each chunk -> b64 p-read, b64 state write, float2 out store.
__global__ void __launch_bounds__(NTHR, 2)
k_fused(const float* __restrict__ u, const float* __restrict__ x0,
        const float* __restrict__ Wx, const float* __restrict__ Wf,
        float* __restrict__ out) {
  __shared__ float tile[RPB * CCH * CSTR];  // 69.6 KB: [row*32+chunk][68]
  __shared__ float Cb[64 * 33];             // 8.4 KB: C[t][i], stride 33
  __shared__ float sbuf[RPB * 32];          // per-row running state slot
  const int tid  = threadIdx.x;
  const int wv   = tid >> 6;
  const int lane = tid & 63;
  const int half = lane >> 5;
  const int k    = lane & 31;
  const int row0 = blockIdx.x * RPB;
  const int lr   = wv * 2 + half;           // phase-3 local row
  const int row  = row0 + lr;

  float wx[OBS];
  #pragma unroll
  for (int i = 0; i < OBS; ++i) wx[i] = Wx[i];
  const float wf = Wf[0];

  // ---- issue all u loads early (land while C is computed)
  float4 stg[16];
  const float* ub = u + (size_t)row0 * NT;
  #pragma unroll
  for (int i = 0; i < 16; ++i) {
    int v = i * NTHR + tid, rr = v >> 9, p = v & 511;
    stg[i] = *(const float4*)(ub + (size_t)rr * NT + 4 * p);
  }

  // ---- C[t][i] (t<64, i<30): homogeneous out at step t from unit state e_i.
  // Redundant per wave (lane&31 = column); wave-0 lanes 0..29 write Cb.
  {
    float r[32];
    #pragma unroll
    for (int i = 0; i < 32; ++i) r[i] = (k < OBS && i == k) ? 1.f : 0.f;
    #pragma unroll
    for (int q = 0; q < 16; ++q)
      #pragma unroll
      for (int e = 0; e < 4; ++e) {
        float o = step6(r, wx, (4 * q + e) & 31, 0.f);
        if (tid < OBS) Cb[(4 * q + e) * 33 + tid] = o;
      }
  }
  // x0 -> state slots (each wave inits its own two rows)
  if (k < OBS) sbuf[lr * 32 + k] = x0[(size_t)row * OBS + k];

  // ---- stage u chunk-major: tile[(row*CCH+chunk)*CSTR + t]
  #pragma unroll
  for (int i = 0; i < 16; ++i) {
    int v = i * NTHR + tid, rr = v >> 9, p = v & 511;
    int c = p >> 4, q = p & 15;
    *(float4*)(&tile[(rr * CCH + c) * CSTR + 4 * q]) = stg[i];
  }
  __syncthreads();

  // ---- phase 2: zero-init particular recurrence; thread <-> chunk (64 steps)
  {
    float r[32];
    #pragma unroll
    for (int i = 0; i < 32; ++i) r[i] = 0.f;
    float* tc = &tile[tid * CSTR];
    #pragma unroll
    for (int q = 0; q < 16; ++q) {
      float4 u4 = *(const float4*)(tc + 4 * q);
      float4 o4;
      o4.x = step6(r, wx, (4 * q + 0) & 31, wf * u4.x);
      o4.y = step6(r, wx, (4 * q + 1) & 31, wf * u4.y);
      o4.z = step6(r, wx, (4 * q + 2) & 31, wf * u4.z);
      o4.w = step6(r, wx, (4 * q + 3) & 31, wf * u4.w);
      *(float4*)(tc + 4 * q) = o4;
    }
  }
  __syncthreads();

  // ---- phase 3 prep: my two C rows (t = 2k, 2k+1)
  float c0[OBS], c1[OBS];
  #pragma unroll
  for (int i = 0; i < OBS; ++i) c0[i] = Cb[(2 * k) * 33 + i];
  #pragma unroll
  for (int i = 0; i < OBS; ++i) c1[i] = Cb[(2 * k + 1) * 33 + i];

  // ---- phase 3: serial chunk scan + correction; both groups in lockstep
  float* sl = &sbuf[lr * 32];
  const float* trow = &tile[(lr * CCH) * CSTR];
  float* orow = out + (size_t)row * NT;
  #pragma unroll 1
  for (int c = 0; c < CCH; ++c) {
    float sv[32];
    #pragma unroll
    for (int q = 0; q < 8; ++q) {      // broadcast b128 (one slot per group)
      float4 v = *(const float4*)(sl + 4 * q);
      sv[4 * q] = v.x; sv[4 * q + 1] = v.y;
      sv[4 * q + 2] = v.z; sv[4 * q + 3] = v.w;
    }
    float2 pq = *(const float2*)(&trow[c * CSTR + 2 * k]);  // particular p
    float a0 = fmaf(c0[0], sv[0], pq.x);
    float a1 = c0[1] * sv[1];
    float a2 = c0[2] * sv[2];
    float b0 = fmaf(c1[0], sv[0], pq.y);
    float b1 = c1[1] * sv[1];
    float b2 = c1[2] * sv[2];
    #pragma unroll
    for (int i = 3; i < OBS; i += 3) {
      a0 = fmaf(c0[i],     sv[i],     a0);
      a1 = fmaf(c0[i + 1], sv[i + 1], a1);
      a2 = fmaf(c0[i + 2], sv[i + 2], a2);
      b0 = fmaf(c1[i],     sv[i],     b0);
      b1 = fmaf(c1[i + 1], sv[i + 1], b1);
      b2 = fmaf(c1[i + 2], sv[i + 2], b2);
    }
    float t0 = a0 + (a1 + a2);         // true out, t = c*64 + 2k
    float t1 = b0 + (b1 + b2);         // true out, t = c*64 + 2k+1
    if (k >= 17)                       // t=34..63 -> next chunk-start state
      *(float2*)(&sl[2 * k - 34]) = make_float2(t0, t1);
    *(float2*)(&orow[c * 64 + 2 * k]) = make_float2(t0, t1);  // 256B/group
    __builtin_amdgcn_wave_barrier();   // fence slot write vs next iter reads
  }
}

extern "C" void kernel_launch(void* const* d_in, const int* in_sizes, int n_in,
                              void* d_out, int out_size, void* d_ws, size_t ws_size,
                              hipStream_t stream) {
  const float* u  = (const float*)d_in[0];
  const float* x0 = (const float*)d_in[1];
  const float* Wx = (const float*)d_in[2];
  const float* Wf = (const float*)d_in[3];
  float* out = (float*)d_out;

  hipLaunchKernelGGL(k_fused, dim3(NB / RPB), dim3(NTHR), 0, stream,
                     u, x0, Wx, Wf, out);
}